// Round 12
// baseline (296.284 us; speedup 1.0000x reference)
//
#include <hip/hip_runtime.h>
#include <stdint.h>

typedef unsigned short u16;
typedef __attribute__((ext_vector_type(8))) short short8;     // 8 bf16 (MFMA A/B frag)
typedef __attribute__((ext_vector_type(4))) float floatx4;    // 16x16 C/D frag
typedef __attribute__((ext_vector_type(16))) float floatx16;  // 32x32 C/D frag

__device__ inline float b2f(u16 u) {
  union { uint32_t i; float f; } x; x.i = ((uint32_t)u) << 16; return x.f;
}
__device__ inline u16 f2b(float f) {
  union { float f; uint32_t i; } x; x.f = f;
  uint32_t r = (x.i + 0x7FFFu + ((x.i >> 16) & 1u)) >> 16;
  return (u16)r;
}
__device__ inline float gelu_f(float v) {
  return 0.5f * v * (1.0f + erff(v * 0.70710678118654752440f));
}

#define MFMA16(a, b, c) __builtin_amdgcn_mfma_f32_16x16x32_bf16((a), (b), (c), 0, 0, 0)
#define MFMA32(a, b, c) __builtin_amdgcn_mfma_f32_32x32x16_bf16((a), (b), (c), 0, 0, 0)

// async global->LDS, 16B per lane; LDS dest must be wave-uniform base + lane*16
__device__ __forceinline__ void gl2lds16(const u16* g, u16* l) {
  __builtin_amdgcn_global_load_lds(
      (const __attribute__((address_space(1))) uint32_t*)(uintptr_t)g,
      (__attribute__((address_space(3))) uint32_t*)(uint32_t)(uintptr_t)l,
      16, 0, 0);
}

// ------------- batched transpose+convert of all 5 weights (fp32 -> bf16^T) -------
__global__ __launch_bounds__(256)
void tpose_all_kernel(const float* __restrict__ W1, const float* __restrict__ W2,
                      const float* __restrict__ Wqkv, const float* __restrict__ Wl,
                      const float* __restrict__ Wo,
                      u16* __restrict__ w1t, u16* __restrict__ w2t,
                      u16* __restrict__ wqkvt, u16* __restrict__ wlt,
                      u16* __restrict__ wot) {
  int id = blockIdx.x;
  const float* src; u16* dst; int R, C, bx, by;
  if (id < 2304)      { src = W2;   dst = w2t;   R = 1536; C = 1536; bx = (id % 48) * 32; by = (id / 48) * 32; }
  else if (id < 2496) { id -= 2304; src = W1;   dst = w1t;   R = 128;  C = 1536; bx = (id % 48) * 32; by = (id / 48) * 32; }
  else if (id < 2688) { id -= 2496; src = Wo;   dst = wot;   R = 1536; C = 128;  bx = (id % 4) * 32;  by = (id / 4) * 32; }
  else if (id < 2736) { id -= 2688; src = Wqkv; dst = wqkvt; R = 128;  C = 384;  bx = (id % 12) * 32; by = (id / 12) * 32; }
  else                { id -= 2736; src = Wl;   dst = wlt;   R = 128;  C = 128;  bx = (id % 4) * 32;  by = (id / 4) * 32; }
  __shared__ u16 t[32][33];
  int tx = threadIdx.x & 31, ty = threadIdx.x >> 5;
  for (int i = 0; i < 32; i += 8)
    t[ty + i][tx] = f2b(src[(size_t)(by + ty + i) * C + bx + tx]);
  __syncthreads();
  for (int i = 0; i < 32; i += 8)
    dst[(size_t)(bx + ty + i) * R + by + tx] = t[tx][ty + i];
}

// ------------- V transpose (bf16): per head, vT[d][n] = qkv_v[n][d]; 4 tiles/blk ---
__global__ __launch_bounds__(256)
void vtrans_kernel(const u16* __restrict__ qkv, u16* __restrict__ vT) {
  int bh = blockIdx.y;                  // b*12+h
  int n0 = blockIdx.x * 32;
  int b = bh / 12, h = bh % 12;
  const int rs = 12 * 384;
  const u16* vp = qkv + (((size_t)b * 1024) * 12 + h) * 384 + 256;
  __shared__ u16 t[4][32][33];
  int tx = threadIdx.x & 31, ty = threadIdx.x >> 5;
  for (int dt = 0; dt < 4; dt++)
    for (int i = 0; i < 32; i += 8)
      t[dt][ty + i][tx] = vp[(size_t)(n0 + ty + i) * rs + dt * 32 + tx];
  __syncthreads();
  u16* dp = vT + (size_t)bh * 128 * 1024 + n0;
  for (int dt = 0; dt < 4; dt++)
    for (int i = 0; i < 32; i += 8)
      dp[(size_t)(dt * 32 + ty + i) * 1024 + tx] = t[dt][tx][ty + i];
}

// ------------- LayerNorm D=128, fp32 source -> bf16 out; one wave per row ---------
__global__ __launch_bounds__(256)
void ln128_f32_kernel(const float* __restrict__ X, const float* __restrict__ g,
                      const float* __restrict__ bb, u16* __restrict__ Y) {
  int tid = threadIdx.x, w = tid >> 6, lane = tid & 63;
  int row = blockIdx.x * 4 + w;
  const float* xr = X + (size_t)row * 128;
  float2 xv = *(const float2*)(xr + lane * 2);
  float x0 = xv.x, x1 = xv.y;
  float s = x0 + x1, s2 = x0 * x0 + x1 * x1;
  for (int m = 1; m < 64; m <<= 1) { s += __shfl_xor(s, m, 64); s2 += __shfl_xor(s2, m, 64); }
  float mean = s * (1.0f / 128.0f);
  float var = s2 * (1.0f / 128.0f) - mean * mean;
  float rstd = 1.0f / sqrtf(var + 1e-5f);
  float2 gv = *(const float2*)(g + lane * 2);
  float2 bv = *(const float2*)(bb + lane * 2);
  float y0 = (x0 - mean) * rstd * gv.x + bv.x;
  float y1 = (x1 - mean) * rstd * gv.y + bv.y;
  *(uint32_t*)(Y + (size_t)row * 128 + lane * 2) =
      (uint32_t)f2b(y0) | ((uint32_t)f2b(y1) << 16);
}

// ------------- LayerNorm D=128, bf16 source -> bf16 out; one wave per row ---------
__global__ __launch_bounds__(256)
void ln128_bf16_kernel(const u16* __restrict__ X, const float* __restrict__ g,
                       const float* __restrict__ bb, u16* __restrict__ Y) {
  int tid = threadIdx.x, w = tid >> 6, lane = tid & 63;
  int row = blockIdx.x * 4 + w;
  const u16* xr = X + (size_t)row * 128;
  uint32_t u = *(const uint32_t*)(xr + lane * 2);
  float x0 = b2f(u & 0xffff), x1 = b2f(u >> 16);
  float s = x0 + x1, s2 = x0 * x0 + x1 * x1;
  for (int m = 1; m < 64; m <<= 1) { s += __shfl_xor(s, m, 64); s2 += __shfl_xor(s2, m, 64); }
  float mean = s * (1.0f / 128.0f);
  float var = s2 * (1.0f / 128.0f) - mean * mean;
  float rstd = 1.0f / sqrtf(var + 1e-5f);
  float2 gv = *(const float2*)(g + lane * 2);
  float2 bv = *(const float2*)(bb + lane * 2);
  float y0 = (x0 - mean) * rstd * gv.x + bv.x;
  float y1 = (x1 - mean) * rstd * gv.y + bv.y;
  *(uint32_t*)(Y + (size_t)row * 128 + lane * 2) =
      (uint32_t)f2b(y0) | ((uint32_t)f2b(y1) << 16);
}

// ------------- LayerNorm D=1536, bf16 source -> bf16 out; one block per row -------
__global__ __launch_bounds__(256)
void ln1536_kernel(const u16* __restrict__ X, const float* __restrict__ g,
                   const float* __restrict__ bb, u16* __restrict__ Y) {
  int row = blockIdx.x, tid = threadIdx.x;
  const u16* xr = X + (size_t)row * 1536;
  uint32_t u0 = *(const uint32_t*)(xr + tid * 6);
  uint32_t u1 = *(const uint32_t*)(xr + tid * 6 + 2);
  uint32_t u2 = *(const uint32_t*)(xr + tid * 6 + 4);
  float v[6] = { b2f(u0 & 0xffff), b2f(u0 >> 16), b2f(u1 & 0xffff),
                 b2f(u1 >> 16),    b2f(u2 & 0xffff), b2f(u2 >> 16) };
  float s = 0.f, s2 = 0.f;
  for (int j = 0; j < 6; j++) { s += v[j]; s2 += v[j] * v[j]; }
  for (int m = 1; m < 64; m <<= 1) { s += __shfl_xor(s, m, 64); s2 += __shfl_xor(s2, m, 64); }
  __shared__ float red[8];
  int w = tid >> 6, lane = tid & 63;
  if (lane == 0) { red[w] = s; red[4 + w] = s2; }
  __syncthreads();
  s = red[0] + red[1] + red[2] + red[3];
  s2 = red[4] + red[5] + red[6] + red[7];
  float mean = s * (1.0f / 1536.0f);
  float var = s2 * (1.0f / 1536.0f) - mean * mean;
  float rstd = 1.0f / sqrtf(var + 1e-5f);
  uint32_t o[3];
  for (int p = 0; p < 3; p++) {
    int c = tid * 6 + p * 2;
    float y0 = (v[p * 2] - mean) * rstd * g[c] + bb[c];
    float y1 = (v[p * 2 + 1] - mean) * rstd * g[c + 1] + bb[c + 1];
    o[p] = (uint32_t)f2b(y0) | ((uint32_t)f2b(y1) << 16);
  }
  u16* yr = Y + (size_t)row * 1536 + tid * 6;
  *(uint32_t*)(yr) = o[0];
  *(uint32_t*)(yr + 2) = o[1];
  *(uint32_t*)(yr + 4) = o[2];
}

// ------------- GEMM 128x128 tile (for large-grid shapes, e.g. QKV) ----------------
template <int GELU, int RES, typename OUTT>
__global__ __launch_bounds__(256)
void gemm_kernel(const u16* __restrict__ A, const u16* __restrict__ BT,
                 const float* __restrict__ bias, const u16* __restrict__ res,
                 OUTT* __restrict__ C, int M, int N, int K) {
  __shared__ __align__(16) u16 abuf[128 * 32];
  __shared__ __align__(16) u16 bbuf[128 * 32];
  int tid = threadIdx.x;
  int w = tid >> 6, lane = tid & 63, ln = lane & 15, quad = lane >> 4;
  int bm = blockIdx.x * 128, bn = blockIdx.y * 128;
  int wr = w >> 1, wc = w & 1;
  floatx4 acc[4][4] = {};
  for (int k0 = 0; k0 < K; k0 += 32) {
    __syncthreads();
    for (int rd = 0; rd < 2; rd++) {
      int c = tid + rd * 256;
      int row = c >> 2, col = (c & 3) * 8;
      gl2lds16(A + (size_t)(bm + row) * K + k0 + col, abuf + c * 8);
      gl2lds16(BT + (size_t)(bn + row) * K + k0 + col, bbuf + c * 8);
    }
    __syncthreads();
    short8 af[4], bf[4];
    for (int i = 0; i < 4; i++)
      af[i] = *(const short8*)(abuf + (wr * 64 + i * 16 + ln) * 32 + quad * 8);
    for (int j = 0; j < 4; j++)
      bf[j] = *(const short8*)(bbuf + (wc * 64 + j * 16 + ln) * 32 + quad * 8);
    for (int i = 0; i < 4; i++)
      for (int j = 0; j < 4; j++)
        acc[i][j] = MFMA16(af[i], bf[j], acc[i][j]);
  }
  for (int i = 0; i < 4; i++) {
    int row0 = bm + wr * 64 + i * 16 + quad * 4;
    for (int j = 0; j < 4; j++) {
      int col = bn + wc * 64 + j * 16 + ln;
      float bv = bias[col];
      for (int r = 0; r < 4; r++) {
        float v = acc[i][j][r] + bv;
        if (RES) v += b2f(res[(size_t)(row0 + r) * N + col]);
        if (GELU) v = gelu_f(v);
        if constexpr (sizeof(OUTT) == 2)
          C[(size_t)(row0 + r) * N + col] = f2b(v);
        else
          C[(size_t)(row0 + r) * N + col] = v;
      }
    }
  }
}

// ------------- GEMM 64x128 tile, BK=32 (short-K shapes) ---------------------------
template <int GELU, int RES, typename OUTT>
__global__ __launch_bounds__(256)
void gemm64_kernel(const u16* __restrict__ A, const u16* __restrict__ BT,
                   const float* __restrict__ bias, const u16* __restrict__ res,
                   OUTT* __restrict__ C, int M, int N, int K) {
  __shared__ __align__(16) u16 abuf[64 * 32];
  __shared__ __align__(16) u16 bbuf[128 * 32];
  int tid = threadIdx.x;
  int w = tid >> 6, lane = tid & 63, ln = lane & 15, quad = lane >> 4;
  int bm = blockIdx.x * 64, bn = blockIdx.y * 128;
  floatx4 acc[4][2] = {};
  for (int k0 = 0; k0 < K; k0 += 32) {
    __syncthreads();
    for (int rd = 0; rd < 2; rd++) {
      int c = tid + rd * 256;
      int row = c >> 2, col = (c & 3) * 8;
      gl2lds16(BT + (size_t)(bn + row) * K + k0 + col, bbuf + c * 8);
    }
    {
      int c = tid;  // 256 chunks = all 64 A rows
      int row = c >> 2, col = (c & 3) * 8;
      gl2lds16(A + (size_t)(bm + row) * K + k0 + col, abuf + c * 8);
    }
    __syncthreads();
    short8 af[4], bf[2];
    for (int i = 0; i < 4; i++)
      af[i] = *(const short8*)(abuf + (i * 16 + ln) * 32 + quad * 8);
    for (int j = 0; j < 2; j++)
      bf[j] = *(const short8*)(bbuf + (w * 32 + j * 16 + ln) * 32 + quad * 8);
    for (int i = 0; i < 4; i++)
      for (int j = 0; j < 2; j++)
        acc[i][j] = MFMA16(af[i], bf[j], acc[i][j]);
  }
  for (int i = 0; i < 4; i++) {
    int row0 = bm + i * 16 + quad * 4;
    for (int j = 0; j < 2; j++) {
      int col = bn + w * 32 + j * 16 + ln;
      float bv = bias[col];
      for (int r = 0; r < 4; r++) {
        float v = acc[i][j][r] + bv;
        if (RES) v += b2f(res[(size_t)(row0 + r) * N + col]);
        if (GELU) v = gelu_f(v);
        if constexpr (sizeof(OUTT) == 2)
          C[(size_t)(row0 + r) * N + col] = f2b(v);
        else
          C[(size_t)(row0 + r) * N + col] = v;
      }
    }
  }
}

// ------------- GEMM 64x128 tile, BK=64 (long-K: W2). Two 32-col LDS planes --------
template <int GELU, int RES, typename OUTT>
__global__ __launch_bounds__(256)
void gemm64b_kernel(const u16* __restrict__ A, const u16* __restrict__ BT,
                    const float* __restrict__ bias, const u16* __restrict__ res,
                    OUTT* __restrict__ C, int M, int N, int K) {
  __shared__ __align__(16) u16 abuf[2 * 64 * 32];    // [ks][row][32]
  __shared__ __align__(16) u16 bbuf[2 * 128 * 32];   // [ks][row][32]
  int tid = threadIdx.x;
  int w = tid >> 6, lane = tid & 63, ln = lane & 15, quad = lane >> 4;
  int bm = blockIdx.x * 64, bn = blockIdx.y * 128;
  floatx4 acc[4][2] = {};
  for (int k0 = 0; k0 < K; k0 += 64) {
    __syncthreads();
    for (int ks = 0; ks < 2; ks++) {
      {
        int c = tid;                       // A plane: 256 chunks = 64 rows
        int row = c >> 2, cc = c & 3;
        gl2lds16(A + (size_t)(bm + row) * K + k0 + ks * 32 + cc * 8,
                 abuf + ks * 2048 + c * 8);
      }
      for (int rd = 0; rd < 2; rd++) {     // B plane: 512 chunks = 128 rows
        int c = tid + rd * 256;
        int row = c >> 2, cc = c & 3;
        gl2lds16(BT + (size_t)(bn + row) * K + k0 + ks * 32 + cc * 8,
                 bbuf + ks * 4096 + c * 8);
      }
    }
    __syncthreads();
    short8 af[2][4], bf[2][2];
    for (int ks = 0; ks < 2; ks++) {
      for (int i = 0; i < 4; i++)
        af[ks][i] = *(const short8*)(abuf + ks * 2048 + (i * 16 + ln) * 32 + quad * 8);
      for (int j = 0; j < 2; j++)
        bf[ks][j] = *(const short8*)(bbuf + ks * 4096 + (w * 32 + j * 16 + ln) * 32 + quad * 8);
    }
    for (int i = 0; i < 4; i++)
      for (int j = 0; j < 2; j++) {
        acc[i][j] = MFMA16(af[0][i], bf[0][j], acc[i][j]);
        acc[i][j] = MFMA16(af[1][i], bf[1][j], acc[i][j]);
      }
  }
  for (int i = 0; i < 4; i++) {
    int row0 = bm + i * 16 + quad * 4;
    for (int j = 0; j < 2; j++) {
      int col = bn + w * 32 + j * 16 + ln;
      float bv = bias[col];
      for (int r = 0; r < 4; r++) {
        float v = acc[i][j][r] + bv;
        if (RES) v += b2f(res[(size_t)(row0 + r) * N + col]);
        if (GELU) v = gelu_f(v);
        if constexpr (sizeof(OUTT) == 2)
          C[(size_t)(row0 + r) * N + col] = f2b(v);
        else
          C[(size_t)(row0 + r) * N + col] = v;
      }
    }
  }
}

// ------------- Wo split-K partial: 64x128 tile, part p = blockIdx.y ----------------
__global__ __launch_bounds__(256)
void gemm64_part_kernel(const u16* __restrict__ A, const u16* __restrict__ BT,
                        float* __restrict__ pws, int Kfull, int kspan) {
  __shared__ __align__(16) u16 abuf[64 * 32];
  __shared__ __align__(16) u16 bbuf[128 * 32];
  int tid = threadIdx.x;
  int w = tid >> 6, lane = tid & 63, ln = lane & 15, quad = lane >> 4;
  int bm = blockIdx.x * 64;
  int kbeg = blockIdx.y * kspan, kend = kbeg + kspan;
  float* Cp = pws + (size_t)blockIdx.y * 4096 * 128;
  floatx4 acc[4][2] = {};
  for (int k0 = kbeg; k0 < kend; k0 += 32) {
    __syncthreads();
    for (int rd = 0; rd < 2; rd++) {
      int c = tid + rd * 256;
      int row = c >> 2, col = (c & 3) * 8;
      gl2lds16(BT + (size_t)row * Kfull + k0 + col, bbuf + c * 8);
    }
    {
      int c = tid;
      int row = c >> 2, col = (c & 3) * 8;
      gl2lds16(A + (size_t)(bm + row) * Kfull + k0 + col, abuf + c * 8);
    }
    __syncthreads();
    short8 af[4], bf[2];
    for (int i = 0; i < 4; i++)
      af[i] = *(const short8*)(abuf + (i * 16 + ln) * 32 + quad * 8);
    for (int j = 0; j < 2; j++)
      bf[j] = *(const short8*)(bbuf + (w * 32 + j * 16 + ln) * 32 + quad * 8);
    for (int i = 0; i < 4; i++)
      for (int j = 0; j < 2; j++)
        acc[i][j] = MFMA16(af[i], bf[j], acc[i][j]);
  }
  for (int i = 0; i < 4; i++) {
    int row0 = bm + i * 16 + quad * 4;
    for (int j = 0; j < 2; j++) {
      int col = w * 32 + j * 16 + ln;
      for (int r = 0; r < 4; r++)
        Cp[(size_t)(row0 + r) * 128 + col] = acc[i][j][r];
    }
  }
}

// combine 4 split-K partials + bias + gelu -> fp32 out  (4096*128 elems)
__global__ __launch_bounds__(256)
void combine_wo_kernel(const float* __restrict__ p, const float* __restrict__ bias,
                       float* __restrict__ out) {
  int i = blockIdx.x * 256 + threadIdx.x;
  const int SZ = 4096 * 128;
  float v = p[i] + p[i + SZ] + p[i + 2 * SZ] + p[i + 3 * SZ] + bias[i & 127];
  out[i] = gelu_f(v);
}

// ------------- Flash attention with 32x32x16 MFMA ---------------------------------
// 256 thr / 4 waves / grid 768 (3 blk/CU). Wave = 32 q-rows x 32-key half;
// key halves merged at end via LDS (fixed-max softmax => partials just add).
// 32x32 MFMA: 2x FLOP per LDS operand byte vs 16x16 -> DS reads per FLOP halve.
// Layouts: A row=lane&31,k=(lane>>5)*8+j ; B col=lane&31,same k ;
// C/D col=lane&31,row=(r&3)+8*(r>>2)+4*(lane>>5) [m74/m101].
// kbuf[kc16][key64][8], vbuf[kc8][d128][8]: conflict-free 8-phase + lane-contig LDS.
__global__ __launch_bounds__(256)
void attn_kernel(const u16* __restrict__ qkv, const u16* __restrict__ vT,
                 u16* __restrict__ obuf) {
  int blk = blockIdx.x;
  int xcd = blk & 7, slot = blk >> 3;
  int bh = xcd * 6 + (slot >> 4);
  int qt = slot & 15;
  int b = bh / 12, hh = bh % 12;
  int tid = threadIdx.x, w = tid >> 6, lane = tid & 63;
  int col = lane & 31, half = lane >> 5;
  int qs = w >> 1, kh = w & 1;   // q-subtile (32 rows), key half (32 keys)
  __shared__ __align__(16) u16 kbuf[16 * 64 * 8];   // 16 KB
  __shared__ __align__(16) u16 vbuf[8 * 128 * 8];   // 16 KB
  __shared__ __align__(16) u16 pbuf[4][32 * 40];    // 10 KB, per wave [q32][40]
  const int rs = 12 * 384;
  size_t base = (((size_t)b * 1024) * 12 + hh) * 384;
  const u16* qp = qkv + base;
  const u16* kp = qkv + base + 128;
  const u16* vp = vT + (size_t)bh * 128 * 1024;

  short8 onesb;  // B col 0 = 1.0
  {
    short v = (col == 0) ? (short)0x3F80 : (short)0;
    for (int j = 0; j < 8; j++) onesb[j] = v;
  }

  int qrow = qt * 64 + qs * 32 + col;
  short8 qf[8];
  for (int kk = 0; kk < 8; kk++)
    qf[kk] = *(const short8*)(qp + (size_t)qrow * rs + kk * 16 + half * 8);

  floatx16 o[4] = {};
  floatx16 ol = {};
  const float K2 = 0.08838834764831845f * 1.4426950408889634f;  // (1/sqrt128)*log2e

  for (int kt = 0; kt < 16; kt++) {
    __syncthreads();
    for (int it = 0; it < 4; it++) {
      int c = it * 256 + tid;            // 1024 chunks each
      int kc = c >> 6, key = c & 63;
      gl2lds16(kp + (size_t)(kt * 64 + key) * rs + kc * 8, kbuf + c * 8);
      int vc = c >> 7, d = c & 127;
      gl2lds16(vp + (size_t)d * 1024 + kt * 64 + vc * 8, vbuf + c * 8);
    }
    __syncthreads();

    // QK^T: S = 32q x 32k (this wave's key half)
    floatx16 s = {};
    for (int kk = 0; kk < 8; kk++) {
      short8 bk = *(const short8*)(kbuf + (kk * 2 + half) * 512 + (kh * 32 + col) * 8);
      s = MFMA32(qf[kk], bk, s);
    }
    // exp -> P in pbuf[w] as [q][40]
    for (int r = 0; r < 16; r++) {
      int q = (r & 3) + 8 * (r >> 2) + 4 * half;
      pbuf[w][q * 40 + col] = f2b(exp2f(s[r] * K2));
    }
    // PV over this wave's 32 keys
    short8 pf[2];
    for (int ks = 0; ks < 2; ks++)
      pf[ks] = *(const short8*)(pbuf[w] + col * 40 + ks * 16 + half * 8);
    for (int ks = 0; ks < 2; ks++) {
      int kc = kh * 4 + ks * 2 + half;
      for (int dt = 0; dt < 4; dt++) {
        short8 bv = *(const short8*)(vbuf + kc * 1024 + (dt * 32 + col) * 8);
        o[dt] = MFMA32(pf[ks], bv, o[dt]);
      }
      ol = MFMA32(pf[ks], onesb, ol);
    }
  }

  // merge key halves: kh=1 wave publishes partials, kh=0 wave combines+writes
  __syncthreads();
  float* mbuf = (float*)(qs == 0 ? (void*)kbuf : (void*)vbuf);
  if (kh == 1) {
    for (int dt = 0; dt < 4; dt++)
      for (int r = 0; r < 16; r++)
        mbuf[(dt * 16 + r) * 64 + lane] = o[dt][r];
    if (col == 0) {
      float* lb = (float*)&pbuf[w][0];
      for (int r = 0; r < 16; r++) {
        int q = (r & 3) + 8 * (r >> 2) + 4 * half;
        lb[q] = ol[r];
      }
    }
  }
  __syncthreads();
  if (kh == 0) {
    const float* lb = (const float*)&pbuf[w + 1][0];
    for (int r = 0; r < 16; r++) {
      int q = (r & 3) + 8 * (r >> 2) + 4 * half;
      float lown = __shfl(ol[r], lane & 32);  // col0 lane of own half
      float inv = 1.0f / (lown + lb[q]);
      int n = qt * 64 + qs * 32 + q;
      size_t ob = ((((size_t)b * 1024 + n) * 12) + hh) * 128;
      for (int dt = 0; dt < 4; dt++) {
        float val = (o[dt][r] + mbuf[(dt * 16 + r) * 64 + lane]) * inv;
        obuf[ob + dt * 32 + col] = f2b(val);
      }
    }
  }
}

// ------------- host ---------------------------------------------------------------
extern "C" void kernel_launch(void* const* d_in, const int* in_sizes, int n_in,
                              void* d_out, int out_size, void* d_ws, size_t ws_size,
                              hipStream_t stream) {
  (void)in_sizes; (void)n_in; (void)out_size; (void)ws_size;
  const float* x    = (const float*)d_in[0];
  const float* ln1g = (const float*)d_in[1];
  const float* ln1b = (const float*)d_in[2];
  const float* W1   = (const float*)d_in[3];
  const float* b1   = (const float*)d_in[4];
  const float* W2   = (const float*)d_in[5];
  const float* b2   = (const float*)d_in[6];
  const float* alng = (const float*)d_in[7];
  const float* alnb = (const float*)d_in[8];
  const float* Wqkv = (const float*)d_in[9];
  const float* bqkv = (const float*)d_in[10];
  const float* Wl   = (const float*)d_in[11];
  const float* bl   = (const float*)d_in[12];
  const float* lnog = (const float*)d_in[13];
  const float* lnob = (const float*)d_in[14];
  const float* Wo   = (const float*)d_in[15];
  const float* bo   = (const float*)d_in[16];
  float* out = (float*)d_out;

  char* ws = (char*)d_ws;
  size_t off = 0;
  auto alloc = [&](size_t elems) { u16* p = (u16*)(ws + off); off += elems * sizeof(u16); return p; };
  u16* w1t   = alloc((size_t)1536 * 128);
  u16* w2t   = alloc((size_t)1536 * 1536);
  u16* wqkvt = alloc((size_t)384 * 128);
  u16* wlt   = alloc((size_t)128 * 128);
  u16* wot   = alloc((size_t)128 * 1536);
  u16* lnx   = alloc((size_t)4096 * 128);
  u16* h1    = alloc((size_t)4096 * 1536);   // obuf; later fp32 split-K partials
  u16* h2    = alloc((size_t)4096 * 1536);
  u16* aln   = alloc((size_t)49152 * 128);   // vT, then feats
  u16* qkv   = alloc((size_t)49152 * 384);   // reused as ln(feats)
  u16* obuf = h1;
  u16* vT = aln;
  u16* feats = aln;
  u16* lnf = qkv;
  float* pws = (float*)h1;  // 4 x 4096 x 128 fp32 = 8 MB <= h1's 12.6 MB (obuf dead)

  dim3 T(256);
  tpose_all_kernel<<<dim3(2752), T, 0, stream>>>(W1, W2, Wqkv, Wl, Wo,
                                                 w1t, w2t, wqkvt, wlt, wot);
  // project
  ln128_f32_kernel<<<dim3(4096 / 4), T, 0, stream>>>(x, ln1g, ln1b, lnx);
  gemm64_kernel<1, 0, u16><<<dim3(4096 / 64, 1536 / 128), T, 0, stream>>>(
      lnx, w1t, b1, nullptr, h1, 4096, 1536, 128);
  gemm64b_kernel<0, 0, u16><<<dim3(4096 / 64, 1536 / 128), T, 0, stream>>>(
      h1, w2t, b2, nullptr, h2, 4096, 1536, 1536);
  // attention
  ln128_bf16_kernel<<<dim3(49152 / 4), T, 0, stream>>>(h2, alng, alnb, aln);
  gemm_kernel<0, 0, u16><<<dim3(49152 / 128, 384 / 128), T, 0, stream>>>(
      aln, wqkvt, bqkv, nullptr, qkv, 49152, 384, 128);
  vtrans_kernel<<<dim3(1024 / 32, 48), T, 0, stream>>>(qkv, vT);
  attn_kernel<<<dim3(768), T, 0, stream>>>(qkv, vT, obuf);
  gemm64_kernel<1, 1, u16><<<dim3(49152 / 64, 1), T, 0, stream>>>(
      obuf, wlt, bl, h2, feats, 49152, 128, 128);
  // out_proj: LN1536 -> split-K x4 (64-row tiles, 256 blocks) -> combine
  ln1536_kernel<<<dim3(4096), T, 0, stream>>>(feats, lnog, lnob, lnf);
  gemm64_part_kernel<<<dim3(4096 / 64, 4), T, 0, stream>>>(lnf, wot, pws, 1536, 384);
  combine_wo_kernel<<<dim3(4096 * 128 / 256), T, 0, stream>>>(pws, bo, out);
}

// Round 13
// 253.998 us; speedup vs baseline: 1.1665x; 1.1665x over previous
//
#include <hip/hip_runtime.h>
#include <stdint.h>

typedef unsigned short u16;
typedef __attribute__((ext_vector_type(8))) short short8;   // 8 bf16 (MFMA A/B frag)
typedef __attribute__((ext_vector_type(4))) float floatx4;  // MFMA C/D frag

__device__ inline float b2f(u16 u) {
  union { uint32_t i; float f; } x; x.i = ((uint32_t)u) << 16; return x.f;
}
__device__ inline u16 f2b(float f) {
  union { float f; uint32_t i; } x; x.f = f;
  uint32_t r = (x.i + 0x7FFFu + ((x.i >> 16) & 1u)) >> 16;
  return (u16)r;
}
__device__ inline float gelu_f(float v) {
  return 0.5f * v * (1.0f + erff(v * 0.70710678118654752440f));
}

#define MFMA16(a, b, c) __builtin_amdgcn_mfma_f32_16x16x32_bf16((a), (b), (c), 0, 0, 0)

// async global->LDS, 16B per lane; LDS dest must be wave-uniform base + lane*16
__device__ __forceinline__ void gl2lds16(const u16* g, u16* l) {
  __builtin_amdgcn_global_load_lds(
      (const __attribute__((address_space(1))) uint32_t*)(uintptr_t)g,
      (__attribute__((address_space(3))) uint32_t*)(uint32_t)(uintptr_t)l,
      16, 0, 0);
}

// ------------- batched transpose+convert of all 5 weights (fp32 -> bf16^T) -------
__global__ __launch_bounds__(256)
void tpose_all_kernel(const float* __restrict__ W1, const float* __restrict__ W2,
                      const float* __restrict__ Wqkv, const float* __restrict__ Wl,
                      const float* __restrict__ Wo,
                      u16* __restrict__ w1t, u16* __restrict__ w2t,
                      u16* __restrict__ wqkvt, u16* __restrict__ wlt,
                      u16* __restrict__ wot) {
  int id = blockIdx.x;
  const float* src; u16* dst; int R, C, bx, by;
  if (id < 2304)      { src = W2;   dst = w2t;   R = 1536; C = 1536; bx = (id % 48) * 32; by = (id / 48) * 32; }
  else if (id < 2496) { id -= 2304; src = W1;   dst = w1t;   R = 128;  C = 1536; bx = (id % 48) * 32; by = (id / 48) * 32; }
  else if (id < 2688) { id -= 2496; src = Wo;   dst = wot;   R = 1536; C = 128;  bx = (id % 4) * 32;  by = (id / 4) * 32; }
  else if (id < 2736) { id -= 2688; src = Wqkv; dst = wqkvt; R = 128;  C = 384;  bx = (id % 12) * 32; by = (id / 12) * 32; }
  else                { id -= 2736; src = Wl;   dst = wlt;   R = 128;  C = 128;  bx = (id % 4) * 32;  by = (id / 4) * 32; }
  __shared__ u16 t[32][33];
  int tx = threadIdx.x & 31, ty = threadIdx.x >> 5;
  for (int i = 0; i < 32; i += 8)
    t[ty + i][tx] = f2b(src[(size_t)(by + ty + i) * C + bx + tx]);
  __syncthreads();
  for (int i = 0; i < 32; i += 8)
    dst[(size_t)(bx + ty + i) * R + by + tx] = t[tx][ty + i];
}

// ------------- LayerNorm D=128, fp32 source -> bf16 out; one wave per row ---------
__global__ __launch_bounds__(256)
void ln128_f32_kernel(const float* __restrict__ X, const float* __restrict__ g,
                      const float* __restrict__ bb, u16* __restrict__ Y) {
  int tid = threadIdx.x, w = tid >> 6, lane = tid & 63;
  int row = blockIdx.x * 4 + w;
  const float* xr = X + (size_t)row * 128;
  float2 xv = *(const float2*)(xr + lane * 2);
  float x0 = xv.x, x1 = xv.y;
  float s = x0 + x1, s2 = x0 * x0 + x1 * x1;
  for (int m = 1; m < 64; m <<= 1) { s += __shfl_xor(s, m, 64); s2 += __shfl_xor(s2, m, 64); }
  float mean = s * (1.0f / 128.0f);
  float var = s2 * (1.0f / 128.0f) - mean * mean;
  float rstd = 1.0f / sqrtf(var + 1e-5f);
  float2 gv = *(const float2*)(g + lane * 2);
  float2 bv = *(const float2*)(bb + lane * 2);
  float y0 = (x0 - mean) * rstd * gv.x + bv.x;
  float y1 = (x1 - mean) * rstd * gv.y + bv.y;
  *(uint32_t*)(Y + (size_t)row * 128 + lane * 2) =
      (uint32_t)f2b(y0) | ((uint32_t)f2b(y1) << 16);
}

// ------------- per-head LN D=128 with (b,n,h) -> (b,h,n) permuted output ----------
// out row rid=(b*12+h)*1024+n reads h2[b][n][h*128..], writes Y[rid][128]
__global__ __launch_bounds__(256)
void ln128_perm_kernel(const u16* __restrict__ X, const float* __restrict__ g,
                       const float* __restrict__ bb, u16* __restrict__ Y) {
  int tid = threadIdx.x, w = tid >> 6, lane = tid & 63;
  int rid = blockIdx.x * 4 + w;
  int bh = rid >> 10, n = rid & 1023;
  int b = bh / 12, h = bh % 12;
  const u16* xr = X + ((size_t)(b * 1024 + n)) * 1536 + h * 128;
  uint32_t u = *(const uint32_t*)(xr + lane * 2);
  float x0 = b2f(u & 0xffff), x1 = b2f(u >> 16);
  float s = x0 + x1, s2 = x0 * x0 + x1 * x1;
  for (int m = 1; m < 64; m <<= 1) { s += __shfl_xor(s, m, 64); s2 += __shfl_xor(s2, m, 64); }
  float mean = s * (1.0f / 128.0f);
  float var = s2 * (1.0f / 128.0f) - mean * mean;
  float rstd = 1.0f / sqrtf(var + 1e-5f);
  float2 gv = *(const float2*)(g + lane * 2);
  float2 bv = *(const float2*)(bb + lane * 2);
  float y0 = (x0 - mean) * rstd * gv.x + bv.x;
  float y1 = (x1 - mean) * rstd * gv.y + bv.y;
  *(uint32_t*)(Y + (size_t)rid * 128 + lane * 2) =
      (uint32_t)f2b(y0) | ((uint32_t)f2b(y1) << 16);
}

// ------------- LayerNorm D=1536, bf16 source -> bf16 out; one block per row -------
__global__ __launch_bounds__(256)
void ln1536_kernel(const u16* __restrict__ X, const float* __restrict__ g,
                   const float* __restrict__ bb, u16* __restrict__ Y) {
  int row = blockIdx.x, tid = threadIdx.x;
  const u16* xr = X + (size_t)row * 1536;
  uint32_t u0 = *(const uint32_t*)(xr + tid * 6);
  uint32_t u1 = *(const uint32_t*)(xr + tid * 6 + 2);
  uint32_t u2 = *(const uint32_t*)(xr + tid * 6 + 4);
  float v[6] = { b2f(u0 & 0xffff), b2f(u0 >> 16), b2f(u1 & 0xffff),
                 b2f(u1 >> 16),    b2f(u2 & 0xffff), b2f(u2 >> 16) };
  float s = 0.f, s2 = 0.f;
  for (int j = 0; j < 6; j++) { s += v[j]; s2 += v[j] * v[j]; }
  for (int m = 1; m < 64; m <<= 1) { s += __shfl_xor(s, m, 64); s2 += __shfl_xor(s2, m, 64); }
  __shared__ float red[8];
  int w = tid >> 6, lane = tid & 63;
  if (lane == 0) { red[w] = s; red[4 + w] = s2; }
  __syncthreads();
  s = red[0] + red[1] + red[2] + red[3];
  s2 = red[4] + red[5] + red[6] + red[7];
  float mean = s * (1.0f / 1536.0f);
  float var = s2 * (1.0f / 1536.0f) - mean * mean;
  float rstd = 1.0f / sqrtf(var + 1e-5f);
  uint32_t o[3];
  for (int p = 0; p < 3; p++) {
    int c = tid * 6 + p * 2;
    float y0 = (v[p * 2] - mean) * rstd * g[c] + bb[c];
    float y1 = (v[p * 2 + 1] - mean) * rstd * g[c + 1] + bb[c + 1];
    o[p] = (uint32_t)f2b(y0) | ((uint32_t)f2b(y1) << 16);
  }
  u16* yr = Y + (size_t)row * 1536 + tid * 6;
  *(uint32_t*)(yr) = o[0];
  *(uint32_t*)(yr + 2) = o[1];
  *(uint32_t*)(yr + 4) = o[2];
}

// ------------- QKV GEMM 128x128 tile; A rows in (b,h,n) order ---------------------
// blockIdx.y 0,1: write q,k into qkv[row][256]; blockIdx.y 2: write V DIRECTLY
// TRANSPOSED into vT[bh][d][n] (4 consecutive n per reg group -> aligned 8B stores).
__global__ __launch_bounds__(256)
void qkv_kernel(const u16* __restrict__ A, const u16* __restrict__ BT,
                const float* __restrict__ bias, u16* __restrict__ qkv,
                u16* __restrict__ vT) {
  const int K = 128;
  __shared__ __align__(16) u16 abuf[128 * 32];
  __shared__ __align__(16) u16 bbuf[128 * 32];
  int tid = threadIdx.x;
  int w = tid >> 6, lane = tid & 63, ln = lane & 15, quad = lane >> 4;
  int bm = blockIdx.x * 128, bn = blockIdx.y * 128;
  int wr = w >> 1, wc = w & 1;
  floatx4 acc[4][4] = {};
  for (int k0 = 0; k0 < K; k0 += 32) {
    __syncthreads();
    for (int rd = 0; rd < 2; rd++) {
      int c = tid + rd * 256;
      int row = c >> 2, col = (c & 3) * 8;
      gl2lds16(A + (size_t)(bm + row) * K + k0 + col, abuf + c * 8);
      gl2lds16(BT + (size_t)(bn + row) * K + k0 + col, bbuf + c * 8);
    }
    __syncthreads();
    short8 af[4], bf[4];
    for (int i = 0; i < 4; i++)
      af[i] = *(const short8*)(abuf + (wr * 64 + i * 16 + ln) * 32 + quad * 8);
    for (int j = 0; j < 4; j++)
      bf[j] = *(const short8*)(bbuf + (wc * 64 + j * 16 + ln) * 32 + quad * 8);
    for (int i = 0; i < 4; i++)
      for (int j = 0; j < 4; j++)
        acc[i][j] = MFMA16(af[i], bf[j], acc[i][j]);
  }
  if (blockIdx.y < 2) {
    for (int i = 0; i < 4; i++) {
      int row0 = bm + wr * 64 + i * 16 + quad * 4;
      for (int j = 0; j < 4; j++) {
        int col = bn + wc * 64 + j * 16 + ln;
        float bv = bias[col];
        for (int r = 0; r < 4; r++)
          qkv[(size_t)(row0 + r) * 256 + col] = f2b(acc[i][j][r] + bv);
      }
    }
  } else {
    int bh = bm >> 10;                 // block fully inside one (b,h): 1024 rows/bh
    int nb = bm & 1023;
    u16* vp = vT + (size_t)bh * 128 * 1024;
    for (int i = 0; i < 4; i++) {
      int n0 = nb + wr * 64 + i * 16 + quad * 4;
      for (int j = 0; j < 4; j++) {
        int d = wc * 64 + j * 16 + ln;
        float bv = bias[256 + d];
        u16 tmp[4];
        for (int r = 0; r < 4; r++) tmp[r] = f2b(acc[i][j][r] + bv);
        *(uint2*)(vp + (size_t)d * 1024 + n0) = *(const uint2*)tmp;
      }
    }
  }
}

// ------------- GEMM 64x128 tile, BK=32 (W1) ---------------------------------------
template <int GELU, int RES, typename OUTT>
__global__ __launch_bounds__(256)
void gemm64_kernel(const u16* __restrict__ A, const u16* __restrict__ BT,
                   const float* __restrict__ bias, const u16* __restrict__ res,
                   OUTT* __restrict__ C, int M, int N, int K) {
  __shared__ __align__(16) u16 abuf[64 * 32];
  __shared__ __align__(16) u16 bbuf[128 * 32];
  int tid = threadIdx.x;
  int w = tid >> 6, lane = tid & 63, ln = lane & 15, quad = lane >> 4;
  int bm = blockIdx.x * 64, bn = blockIdx.y * 128;
  floatx4 acc[4][2] = {};
  for (int k0 = 0; k0 < K; k0 += 32) {
    __syncthreads();
    for (int rd = 0; rd < 2; rd++) {
      int c = tid + rd * 256;
      int row = c >> 2, col = (c & 3) * 8;
      gl2lds16(BT + (size_t)(bn + row) * K + k0 + col, bbuf + c * 8);
    }
    {
      int c = tid;
      int row = c >> 2, col = (c & 3) * 8;
      gl2lds16(A + (size_t)(bm + row) * K + k0 + col, abuf + c * 8);
    }
    __syncthreads();
    short8 af[4], bf[2];
    for (int i = 0; i < 4; i++)
      af[i] = *(const short8*)(abuf + (i * 16 + ln) * 32 + quad * 8);
    for (int j = 0; j < 2; j++)
      bf[j] = *(const short8*)(bbuf + (w * 32 + j * 16 + ln) * 32 + quad * 8);
    for (int i = 0; i < 4; i++)
      for (int j = 0; j < 2; j++)
        acc[i][j] = MFMA16(af[i], bf[j], acc[i][j]);
  }
  for (int i = 0; i < 4; i++) {
    int row0 = bm + i * 16 + quad * 4;
    for (int j = 0; j < 2; j++) {
      int col = bn + w * 32 + j * 16 + ln;
      float bv = bias[col];
      for (int r = 0; r < 4; r++) {
        float v = acc[i][j][r] + bv;
        if (RES) v += b2f(res[(size_t)(row0 + r) * N + col]);
        if (GELU) v = gelu_f(v);
        if constexpr (sizeof(OUTT) == 2)
          C[(size_t)(row0 + r) * N + col] = f2b(v);
        else
          C[(size_t)(row0 + r) * N + col] = v;
      }
    }
  }
}

// ------------- GEMM 64x128 tile, BK=64 (long-K: W2). Two 32-col LDS planes --------
template <int GELU, int RES, typename OUTT>
__global__ __launch_bounds__(256)
void gemm64b_kernel(const u16* __restrict__ A, const u16* __restrict__ BT,
                    const float* __restrict__ bias, const u16* __restrict__ res,
                    OUTT* __restrict__ C, int M, int N, int K) {
  __shared__ __align__(16) u16 abuf[2 * 64 * 32];
  __shared__ __align__(16) u16 bbuf[2 * 128 * 32];
  int tid = threadIdx.x;
  int w = tid >> 6, lane = tid & 63, ln = lane & 15, quad = lane >> 4;
  int bm = blockIdx.x * 64, bn = blockIdx.y * 128;
  floatx4 acc[4][2] = {};
  for (int k0 = 0; k0 < K; k0 += 64) {
    __syncthreads();
    for (int ks = 0; ks < 2; ks++) {
      {
        int c = tid;
        int row = c >> 2, cc = c & 3;
        gl2lds16(A + (size_t)(bm + row) * K + k0 + ks * 32 + cc * 8,
                 abuf + ks * 2048 + c * 8);
      }
      for (int rd = 0; rd < 2; rd++) {
        int c = tid + rd * 256;
        int row = c >> 2, cc = c & 3;
        gl2lds16(BT + (size_t)(bn + row) * K + k0 + ks * 32 + cc * 8,
                 bbuf + ks * 4096 + c * 8);
      }
    }
    __syncthreads();
    short8 af[2][4], bf[2][2];
    for (int ks = 0; ks < 2; ks++) {
      for (int i = 0; i < 4; i++)
        af[ks][i] = *(const short8*)(abuf + ks * 2048 + (i * 16 + ln) * 32 + quad * 8);
      for (int j = 0; j < 2; j++)
        bf[ks][j] = *(const short8*)(bbuf + ks * 4096 + (w * 32 + j * 16 + ln) * 32 + quad * 8);
    }
    for (int i = 0; i < 4; i++)
      for (int j = 0; j < 2; j++) {
        acc[i][j] = MFMA16(af[0][i], bf[0][j], acc[i][j]);
        acc[i][j] = MFMA16(af[1][i], bf[1][j], acc[i][j]);
      }
  }
  for (int i = 0; i < 4; i++) {
    int row0 = bm + i * 16 + quad * 4;
    for (int j = 0; j < 2; j++) {
      int col = bn + w * 32 + j * 16 + ln;
      float bv = bias[col];
      for (int r = 0; r < 4; r++) {
        float v = acc[i][j][r] + bv;
        if (RES) v += b2f(res[(size_t)(row0 + r) * N + col]);
        if (GELU) v = gelu_f(v);
        if constexpr (sizeof(OUTT) == 2)
          C[(size_t)(row0 + r) * N + col] = f2b(v);
        else
          C[(size_t)(row0 + r) * N + col] = v;
      }
    }
  }
}

// ------------- Wl GEMM 64x128: A rows (b,h,n); epilogue remaps to feats (b,n,h) ---
// feats[(b*1024+n)*1536 + h*128 + col] = gelu(acc + bias + h2[same idx])
__global__ __launch_bounds__(256)
void gemmwl_kernel(const u16* __restrict__ A, const u16* __restrict__ BT,
                   const float* __restrict__ bias, const u16* __restrict__ res,
                   u16* __restrict__ feats) {
  const int K = 128;
  __shared__ __align__(16) u16 abuf[64 * 32];
  __shared__ __align__(16) u16 bbuf[128 * 32];
  int tid = threadIdx.x;
  int w = tid >> 6, lane = tid & 63, ln = lane & 15, quad = lane >> 4;
  int bm = blockIdx.x * 64;
  floatx4 acc[4][2] = {};
  for (int k0 = 0; k0 < K; k0 += 32) {
    __syncthreads();
    for (int rd = 0; rd < 2; rd++) {
      int c = tid + rd * 256;
      int row = c >> 2, col = (c & 3) * 8;
      gl2lds16(BT + (size_t)row * K + k0 + col, bbuf + c * 8);
    }
    {
      int c = tid;
      int row = c >> 2, col = (c & 3) * 8;
      gl2lds16(A + (size_t)(bm + row) * K + k0 + col, abuf + c * 8);
    }
    __syncthreads();
    short8 af[4], bf[2];
    for (int i = 0; i < 4; i++)
      af[i] = *(const short8*)(abuf + (i * 16 + ln) * 32 + quad * 8);
    for (int j = 0; j < 2; j++)
      bf[j] = *(const short8*)(bbuf + (w * 32 + j * 16 + ln) * 32 + quad * 8);
    for (int i = 0; i < 4; i++)
      for (int j = 0; j < 2; j++)
        acc[i][j] = MFMA16(af[i], bf[j], acc[i][j]);
  }
  int bh = bm >> 10, nb = bm & 1023;   // 64-row block within one (b,h)
  int b = bh / 12, hh = bh % 12;
  size_t obase = ((size_t)b * 1024) * 1536 + hh * 128;
  for (int i = 0; i < 4; i++) {
    int n0 = nb + i * 16 + quad * 4;
    for (int j = 0; j < 2; j++) {
      int col = w * 32 + j * 16 + ln;
      float bv = bias[col];
      for (int r = 0; r < 4; r++) {
        size_t idx = obase + (size_t)(n0 + r) * 1536 + col;
        float v = acc[i][j][r] + bv + b2f(res[idx]);
        feats[idx] = f2b(gelu_f(v));
      }
    }
  }
}

// ------------- Wo split-K partial: 64x128 tile, part p = blockIdx.y ----------------
__global__ __launch_bounds__(256)
void gemm64_part_kernel(const u16* __restrict__ A, const u16* __restrict__ BT,
                        float* __restrict__ pws, int Kfull, int kspan) {
  __shared__ __align__(16) u16 abuf[64 * 32];
  __shared__ __align__(16) u16 bbuf[128 * 32];
  int tid = threadIdx.x;
  int w = tid >> 6, lane = tid & 63, ln = lane & 15, quad = lane >> 4;
  int bm = blockIdx.x * 64;
  int kbeg = blockIdx.y * kspan, kend = kbeg + kspan;
  float* Cp = pws + (size_t)blockIdx.y * 4096 * 128;
  floatx4 acc[4][2] = {};
  for (int k0 = kbeg; k0 < kend; k0 += 32) {
    __syncthreads();
    for (int rd = 0; rd < 2; rd++) {
      int c = tid + rd * 256;
      int row = c >> 2, col = (c & 3) * 8;
      gl2lds16(BT + (size_t)row * Kfull + k0 + col, bbuf + c * 8);
    }
    {
      int c = tid;
      int row = c >> 2, col = (c & 3) * 8;
      gl2lds16(A + (size_t)(bm + row) * Kfull + k0 + col, abuf + c * 8);
    }
    __syncthreads();
    short8 af[4], bf[2];
    for (int i = 0; i < 4; i++)
      af[i] = *(const short8*)(abuf + (i * 16 + ln) * 32 + quad * 8);
    for (int j = 0; j < 2; j++)
      bf[j] = *(const short8*)(bbuf + (w * 32 + j * 16 + ln) * 32 + quad * 8);
    for (int i = 0; i < 4; i++)
      for (int j = 0; j < 2; j++)
        acc[i][j] = MFMA16(af[i], bf[j], acc[i][j]);
  }
  for (int i = 0; i < 4; i++) {
    int row0 = bm + i * 16 + quad * 4;
    for (int j = 0; j < 2; j++) {
      int col = w * 32 + j * 16 + ln;
      for (int r = 0; r < 4; r++)
        Cp[(size_t)(row0 + r) * 128 + col] = acc[i][j][r];
    }
  }
}

// combine 4 split-K partials + bias + gelu -> fp32 out  (4096*128 elems)
__global__ __launch_bounds__(256)
void combine_wo_kernel(const float* __restrict__ p, const float* __restrict__ bias,
                       float* __restrict__ out) {
  int i = blockIdx.x * 256 + threadIdx.x;
  const int SZ = 4096 * 128;
  float v = p[i] + p[i + SZ] + p[i + 2 * SZ] + p[i + 3 * SZ] + bias[i & 127];
  out[i] = gelu_f(v);
}

// ------------- Flash attention (round-9 structure): 64 Q-rows/block, 64-key -------
// qkv: [bh][n][256] bf16 (q 0:128, k 128:256); vT: [bh][128 d][1024 n] bf16
// obuf: [bh][n][128]. Fixed-max softmax, ones-frag l, XCD head grouping.
__global__ __launch_bounds__(256)
void attn_kernel(const u16* __restrict__ qkv, const u16* __restrict__ vT,
                 u16* __restrict__ obuf) {
  int blk = blockIdx.x;
  int xcd = blk & 7, slot = blk >> 3;
  int bh = xcd * 6 + (slot >> 4);
  int qt = slot & 15;
  int tid = threadIdx.x, w = tid >> 6, lane = tid & 63, ln = lane & 15, quad = lane >> 4;
  __shared__ __align__(16) u16 kbuf[4 * 64 * 32];    // [st][key64][32]
  __shared__ __align__(16) u16 vbuf[2 * 128 * 32];   // [kf][d128][32]
  __shared__ __align__(16) u16 pbuf[4][16 * 72];     // per-wave P, padded stride 72
  const int rs = 256;
  size_t base = (size_t)bh * 1024 * 256;
  const u16* qp = qkv + base;
  const u16* kp = qkv + base + 128;
  const u16* vp = vT + (size_t)bh * 128 * 1024;

  short8 onesb;
  {
    short v = (ln == 0) ? (short)0x3F80 : (short)0;
    for (int j = 0; j < 8; j++) onesb[j] = v;
  }

  int qrow = qt * 64 + w * 16 + ln;
  short8 qf[4];
  for (int st = 0; st < 4; st++)
    qf[st] = *(const short8*)(qp + (size_t)qrow * rs + st * 32 + quad * 8);

  floatx4 o[9] = {};
  const float K2 = 0.08838834764831845f * 1.4426950408889634f;  // (1/sqrt128)*log2e

  for (int kt = 0; kt < 16; kt++) {
    __syncthreads();
    for (int it = 0; it < 4; it++) {
      int c = it * 256 + tid;           // 1024 chunks each for K and V
      int st = c >> 8, key = (c >> 2) & 63, cc = c & 3;
      gl2lds16(kp + (size_t)(kt * 64 + key) * rs + st * 32 + cc * 8, kbuf + c * 8);
      int kf = c >> 9, d = (c >> 2) & 127;
      gl2lds16(vp + (size_t)d * 1024 + kt * 64 + kf * 32 + cc * 8, vbuf + c * 8);
    }
    __syncthreads();

    floatx4 s[4] = {};
    for (int t = 0; t < 4; t++)
      for (int st = 0; st < 4; st++) {
        short8 bk = *(const short8*)(kbuf + st * 2048 + (t * 16 + ln) * 32 + quad * 8);
        s[t] = MFMA16(qf[st], bk, s[t]);
      }
    for (int r = 0; r < 4; r++) {
      int prow = (quad * 4 + r) * 72;
      pbuf[w][prow + ln]      = f2b(exp2f(s[0][r] * K2));
      pbuf[w][prow + 16 + ln] = f2b(exp2f(s[1][r] * K2));
      pbuf[w][prow + 32 + ln] = f2b(exp2f(s[2][r] * K2));
      pbuf[w][prow + 48 + ln] = f2b(exp2f(s[3][r] * K2));
    }
    for (int kf = 0; kf < 2; kf++) {
      short8 ap = *(const short8*)(&pbuf[w][ln * 72 + kf * 32 + quad * 8]);
      for (int dt = 0; dt < 8; dt++) {
        short8 bv = *(const short8*)(vbuf + kf * 4096 + (dt * 16 + ln) * 32 + quad * 8);
        o[dt] = MFMA16(ap, bv, o[dt]);
      }
      o[8] = MFMA16(ap, onesb, o[8]);
    }
  }

  for (int r = 0; r < 4; r++) {
    float l = __shfl(o[8][r], lane & 48);  // ones-column at ln==0 of each quad
    float inv = 1.0f / l;
    int n = qt * 64 + w * 16 + quad * 4 + r;
    size_t ob = ((size_t)bh * 1024 + n) * 128;
    for (int dt = 0; dt < 8; dt++)
      obuf[ob + dt * 16 + ln] = f2b(o[dt][r] * inv);
  }
}

// ------------- host ---------------------------------------------------------------
extern "C" void kernel_launch(void* const* d_in, const int* in_sizes, int n_in,
                              void* d_out, int out_size, void* d_ws, size_t ws_size,
                              hipStream_t stream) {
  (void)in_sizes; (void)n_in; (void)out_size; (void)ws_size;
  const float* x    = (const float*)d_in[0];
  const float* ln1g = (const float*)d_in[1];
  const float* ln1b = (const float*)d_in[2];
  const float* W1   = (const float*)d_in[3];
  const float* b1   = (const float*)d_in[4];
  const float* W2   = (const float*)d_in[5];
  const float* b2   = (const float*)d_in[6];
  const float* alng = (const float*)d_in[7];
  const float* alnb = (const float*)d_in[8];
  const float* Wqkv = (const float*)d_in[9];
  const float* bqkv = (const float*)d_in[10];
  const float* Wl   = (const float*)d_in[11];
  const float* bl   = (const float*)d_in[12];
  const float* lnog = (const float*)d_in[13];
  const float* lnob = (const float*)d_in[14];
  const float* Wo   = (const float*)d_in[15];
  const float* bo   = (const float*)d_in[16];
  float* out = (float*)d_out;

  char* ws = (char*)d_ws;
  size_t off = 0;
  auto alloc = [&](size_t elems) { u16* p = (u16*)(ws + off); off += elems * sizeof(u16); return p; };
  u16* w1t   = alloc((size_t)1536 * 128);
  u16* w2t   = alloc((size_t)1536 * 1536);
  u16* wqkvt = alloc((size_t)384 * 128);
  u16* wlt   = alloc((size_t)128 * 128);
  u16* wot   = alloc((size_t)128 * 1536);
  u16* lnx   = alloc((size_t)4096 * 128);
  u16* h1    = alloc((size_t)4096 * 1536);   // W1-out; then vT; then fp32 pws
  u16* h2    = alloc((size_t)4096 * 1536);
  u16* aln   = alloc((size_t)49152 * 128);   // LN-perm out; then feats
  u16* qkv   = alloc((size_t)49152 * 256);   // q,k only; later lnf
  u16* obuf  = alloc((size_t)49152 * 128);
  u16* vT = h1;        // h1 dead after W2 reads it; vT written by qkv_kernel
  u16* feats = aln;    // aln dead after qkv_kernel
  u16* lnf = qkv;      // qkv dead after attn
  float* pws = (float*)h1;  // vT dead after attn; 8 MB <= 12.6 MB

  dim3 T(256);
  tpose_all_kernel<<<dim3(2752), T, 0, stream>>>(W1, W2, Wqkv, Wl, Wo,
                                                 w1t, w2t, wqkvt, wlt, wot);
  // project
  ln128_f32_kernel<<<dim3(4096 / 4), T, 0, stream>>>(x, ln1g, ln1b, lnx);
  gemm64_kernel<1, 0, u16><<<dim3(4096 / 64, 1536 / 128), T, 0, stream>>>(
      lnx, w1t, b1, nullptr, h1, 4096, 1536, 128);
  gemm64b_kernel<0, 0, u16><<<dim3(4096 / 64, 1536 / 128), T, 0, stream>>>(
      h1, w2t, b2, nullptr, h2, 4096, 1536, 1536);
  // attention: per-head LN (permuted to (b,h,n)) -> QKV GEMM (V direct to vT)
  ln128_perm_kernel<<<dim3(49152 / 4), T, 0, stream>>>(h2, alng, alnb, aln);
  qkv_kernel<<<dim3(49152 / 128, 3), T, 0, stream>>>(aln, wqkvt, bqkv, qkv, vT);
  attn_kernel<<<dim3(768), T, 0, stream>>>(qkv, vT, obuf);
  gemmwl_kernel<<<dim3(49152 / 64), T, 0, stream>>>(obuf, wlt, bl, h2, feats);
  // out_proj: LN1536 -> split-K x4 -> combine
  ln1536_kernel<<<dim3(4096), T, 0, stream>>>(feats, lnog, lnob, lnf);
  gemm64_part_kernel<<<dim3(4096 / 64, 4), T, 0, stream>>>(lnf, wot, pws, 1536, 384);
  combine_wo_kernel<<<dim3(4096 * 128 / 256), T, 0, stream>>>(pws, bo, out);
}